// Round 5
// baseline (15552.751 us; speedup 1.0000x reference)
//
#include <hip/hip_runtime.h>

// Problem constants
constexpr int BB = 128;   // batch
constexpr int TPp = 128;  // premise len
constexpr int THh = 64;   // hypothesis len
constexpr int HH = 512;   // hidden

// ---------------- workspace layout (fp32 words) ----------------
constexpr size_t OFF_HS     = 0;                               // premise h history [b][t][512]
constexpr size_t SZ_HS      = (size_t)16384 * 512;
constexpr size_t OFF_HT     = OFF_HS + SZ_HS;                  // hyp h history TRANSPOSED [t][j][b]
constexpr size_t SZ_HT      = (size_t)8192 * 512;
constexpr size_t OFF_WSM    = OFF_HT + SZ_HT;                  // Ws [16384][512] (match) / LSTM private xg
constexpr size_t SZ_WSM     = (size_t)16384 * 512;
constexpr size_t OFF_WIHT_P = OFF_WSM + SZ_WSM;                // [304 k][2048 c] rows 300-302 zero, 303=bih+bhh
constexpr size_t SZ_WIHT    = (size_t)304 * 2048;
constexpr size_t OFF_WIHT_H = OFF_WIHT_P + SZ_WIHT;
constexpr size_t OFF_WHHT_P = OFF_WIHT_H + SZ_WIHT;            // WSTK_P [128 li][512 k][16 c] c=jj*4+g
constexpr size_t OFF_WHHT_H = OFF_WHHT_P + (size_t)512 * 2048;
constexpr size_t OFF_WB1T   = OFF_WHHT_H + (size_t)512 * 2048; // [2560 c][1024 k]
constexpr size_t OFF_WIA    = OFF_WB1T + (size_t)2560 * 1024;  // WIAT [2048 c][512 k], c=j*4+g
constexpr size_t OFF_WEF    = OFF_WIA + (size_t)2048 * 512;    // w_e [512]
constexpr size_t OFF_BM     = OFF_WEF + 512;                   // bih_m+bhh_m [2048]
constexpr size_t OFF_HC_P   = OFF_BM + 2048;                   // 2 x [128][512] h carry dbuf (premise)
constexpr size_t OFF_HC_H   = OFF_HC_P + 2 * (size_t)BB * HH;  // 2 x [128][512] (hyp)
constexpr size_t OFF_C_P    = OFF_HC_H + 2 * (size_t)BB * HH;  // vestigial (zeroed)
constexpr size_t OFF_C_H    = OFF_C_P + (size_t)BB * HH;
constexpr size_t OFF_Q      = OFF_C_H + (size_t)BB * HH;       // qT [512 c][128 r]
constexpr size_t OFF_GH     = OFF_Q + (size_t)BB * HH;         // ghT [2048 c][128 r], c=j*4+g
constexpr size_t OFF_A      = OFF_GH + (size_t)BB * 2048;      // abufT [512 j][128 r]
constexpr size_t OFF_HM     = OFF_A + (size_t)BB * HH;         // hmT [512 j][128 r]
constexpr size_t OFF_CM     = OFF_HM + (size_t)BB * HH;        // vestigial (zeroed)
constexpr size_t OFF_LAST   = OFF_CM + (size_t)BB * HH;        // [128 r][512 j]
constexpr size_t OFF_BARP   = OFF_LAST + (size_t)BB * HH;      // premise barrier slots (2560)
constexpr size_t OFF_BARH   = OFF_BARP + 2560;                 // hyp barrier slots (2560)
constexpr size_t OFF_BARF   = OFF_BARH + 2560;                 // unused (4352, zeroed)
constexpr size_t OFF_BARM   = OFF_BARF + 4352;                 // match barrier slots (4352)
constexpr size_t WS_FLOATS  = OFF_BARM + 4352;

__device__ __forceinline__ float sigmf(float x) { return 1.0f / (1.0f + __expf(-x)); }
__device__ __forceinline__ float tanh_f(float x) {
  float e = __expf(-2.0f * fabsf(x));
  float r = (1.0f - e) / (1.0f + e);
  return copysignf(r, x);
}

// ---- device-coherent (sc0 sc1) data access: never dirties L2, always at coherence point ----
__device__ __forceinline__ float aload4(const float* p) {
  unsigned u = __hip_atomic_load((const unsigned*)p, __ATOMIC_RELAXED, __HIP_MEMORY_SCOPE_AGENT);
  return __uint_as_float(u);
}
__device__ __forceinline__ void astore4(float* p, float v) {
  __hip_atomic_store((unsigned*)p, __float_as_uint(v), __ATOMIC_RELAXED, __HIP_MEMORY_SCOPE_AGENT);
}
__device__ __forceinline__ float4 aload16(const float* p) {
  const unsigned long long* q = (const unsigned long long*)p;
  unsigned long long u0 = __hip_atomic_load(q, __ATOMIC_RELAXED, __HIP_MEMORY_SCOPE_AGENT);
  unsigned long long u1 = __hip_atomic_load(q + 1, __ATOMIC_RELAXED, __HIP_MEMORY_SCOPE_AGENT);
  union { unsigned long long u; float2 f; } c0, c1;
  c0.u = u0; c1.u = u1;
  float4 f; f.x = c0.f.x; f.y = c0.f.y; f.z = c1.f.x; f.w = c1.f.y;
  return f;
}

// ---- fence-free slot barrier over blocks [base, base+n). NO buffer_wbl2/buffer_inv.
// Correctness: all cross-block data uses device-scope atomics (coherent once vmcnt retires),
// so release = s_waitcnt only. Slots zeroed by k_prep each call (replay-safe).
__device__ __forceinline__ void gbar3(unsigned* bar, int ep, int base, int n) {
  asm volatile("s_waitcnt vmcnt(0) lgkmcnt(0)" ::: "memory");
  __syncthreads();
  const int tid = threadIdx.x;
  const int rel = (int)blockIdx.x - base;
  if (tid == 0)
    __hip_atomic_store(bar + (size_t)rel * 16, (unsigned)ep,
                       __ATOMIC_RELAXED, __HIP_MEMORY_SCOPE_AGENT);
  if (rel == 0) {
    for (int s = tid; s < n; s += (int)blockDim.x)
      while (__hip_atomic_load(bar + (size_t)s * 16,
                               __ATOMIC_RELAXED, __HIP_MEMORY_SCOPE_AGENT) < (unsigned)ep)
        __builtin_amdgcn_s_sleep(1);
    __syncthreads();
    if (tid == 0)
      __hip_atomic_store(bar + (size_t)n * 16, (unsigned)ep,
                         __ATOMIC_RELAXED, __HIP_MEMORY_SCOPE_AGENT);
  } else if (tid == 0) {
    while (__hip_atomic_load(bar + (size_t)n * 16,
                             __ATOMIC_RELAXED, __HIP_MEMORY_SCOPE_AGENT) < (unsigned)ep)
      __builtin_amdgcn_s_sleep(1);
  }
  __syncthreads();
}

// ---------------- diag ----------------
__global__ void k_diag(float* out, float v) {
  int i = blockIdx.x * 64 + threadIdx.x;
  if (i < BB * 3) out[i] = v;
}

// ---------------- K0: weight transpose/stack + state/slot zero ----------------
__global__ __launch_bounds__(256) void k_prep(float* ws,
    const float* Wih_p, const float* bih_p, const float* bhh_p,
    const float* Wih_h, const float* bih_h, const float* bhh_h,
    const float* Whh_p, const float* Whh_h,
    const float* Whh_m, const float* Wih_m, const float* bih_m, const float* bhh_m,
    const float* W_m, const float* W_t, const float* w_e) {
  size_t gid = (size_t)blockIdx.x * 256 + threadIdx.x;
  if (gid < SZ_WIHT) {
    int k = (int)(gid >> 11), r = (int)(gid & 2047);
    float v = (k < 300) ? Wih_p[(size_t)r * 300 + k]
            : (k == 303) ? (bih_p[r] + bhh_p[r]) : 0.f;
    ws[OFF_WIHT_P + gid] = v;
    return;
  }
  gid -= SZ_WIHT;
  if (gid < SZ_WIHT) {
    int k = (int)(gid >> 11), r = (int)(gid & 2047);
    float v = (k < 300) ? Wih_h[(size_t)r * 300 + k]
            : (k == 303) ? (bih_h[r] + bhh_h[r]) : 0.f;
    ws[OFF_WIHT_H + gid] = v;
    return;
  }
  gid -= SZ_WIHT;
  const size_t NT = (size_t)512 * 2048;
  if (gid < NT) {  // WSTK_P
    int li = (int)(gid >> 13);
    int rem = (int)(gid & 8191);
    int k = rem >> 4, c = rem & 15;
    int jj = c >> 2, g = c & 3;
    ws[OFF_WHHT_P + gid] = Whh_p[(size_t)(g * 512 + li * 4 + jj) * 512 + k];
    return;
  }
  gid -= NT;
  if (gid < NT) {  // WSTK_H
    int li = (int)(gid >> 13);
    int rem = (int)(gid & 8191);
    int k = rem >> 4, c = rem & 15;
    int jj = c >> 2, g = c & 3;
    ws[OFF_WHHT_H + gid] = Whh_h[(size_t)(g * 512 + li * 4 + jj) * 512 + k];
    return;
  }
  gid -= NT;
  if (gid < (size_t)2560 * 1024) {  // WB1T [c][k]
    int c = (int)(gid >> 10), k = (int)(gid & 1023);
    float v;
    if (c < 512) {
      v = (k < 512) ? W_m[(size_t)c * 512 + k] : W_t[(size_t)c * 512 + (k - 512)];
    } else {
      int p = c - 512;
      int j = p >> 2, g = p & 3;
      int r = g * 512 + j;
      v = (k < 512) ? Whh_m[(size_t)r * 512 + k] : Wih_m[(size_t)r * 1024 + k];
    }
    ws[OFF_WB1T + gid] = v;
    return;
  }
  gid -= (size_t)2560 * 1024;
  if (gid < (size_t)2048 * 512) {  // WIAT [c][k]
    int c = (int)(gid >> 9), k = (int)(gid & 511);
    int j = c >> 2, g = c & 3;
    ws[OFF_WIA + gid] = Wih_m[((size_t)g * 512 + j) * 1024 + k];
    return;
  }
  gid -= (size_t)2048 * 512;
  if (gid < 512) { ws[OFF_WEF + gid] = w_e[gid]; return; }
  gid -= 512;
  if (gid < 2048) { ws[OFF_BM + gid] = bih_m[gid] + bhh_m[gid]; return; }
  gid -= 2048;
  if (gid < (size_t)393216) { ws[OFF_HC_P + gid] = 0.f; return; }  // HC_P,HC_H,C_P,C_H
  gid -= 393216;
  if (gid < (size_t)131072) { ws[OFF_HM + gid] = 0.f; return; }    // HM, CM
  gid -= 131072;
  if (gid < 13824) { ws[OFF_BARP + gid] = 0.f; return; }           // ALL barrier slots
}

// ---------------- generic 64x64-tile fp32 GEMM (Ws = HS @ W_s^T) ----------------
__global__ __launch_bounds__(256) void k_gemm(const float* __restrict__ A,
                                              const float* __restrict__ Bw, int ldb, int Kdim,
                                              int N, float* __restrict__ C, int ntilesN) {
  __shared__ float As[16][68];
  __shared__ float Bs[16][68];
  const int tid = threadIdx.x;
  const int bid = blockIdx.x;
  const int tm = bid / ntilesN, tn = bid % ntilesN;
  const int m0 = tm * 64, n0 = tn * 64;
  const int tx = tid & 15, ty = tid >> 4;
  const int srow = tid >> 2, skc = (tid & 3) * 4;
  float acc[4][4] = {};
  const float* arowf = A + (size_t)(m0 + srow) * Kdim;
  const float* brow = Bw + (size_t)(n0 + srow) * ldb;
  for (int k0 = 0; k0 < Kdim; k0 += 16) {
    float4 v = *(const float4*)(arowf + k0 + skc);
    As[skc + 0][srow] = v.x; As[skc + 1][srow] = v.y;
    As[skc + 2][srow] = v.z; As[skc + 3][srow] = v.w;
#pragma unroll
    for (int i = 0; i < 4; i++) Bs[skc + i][srow] = brow[k0 + skc + i];
    __syncthreads();
#pragma unroll
    for (int kk = 0; kk < 16; kk++) {
      float4 a4 = *(float4*)&As[kk][ty * 4];
      float4 b4 = *(float4*)&Bs[kk][tx * 4];
      acc[0][0] += a4.x * b4.x; acc[0][1] += a4.x * b4.y; acc[0][2] += a4.x * b4.z; acc[0][3] += a4.x * b4.w;
      acc[1][0] += a4.y * b4.x; acc[1][1] += a4.y * b4.y; acc[1][2] += a4.y * b4.z; acc[1][3] += a4.y * b4.w;
      acc[2][0] += a4.z * b4.x; acc[2][1] += a4.z * b4.y; acc[2][2] += a4.z * b4.z; acc[2][3] += a4.z * b4.w;
      acc[3][0] += a4.w * b4.x; acc[3][1] += a4.w * b4.y; acc[3][2] += a4.w * b4.z; acc[3][3] += a4.w * b4.w;
    }
    __syncthreads();
  }
  const int m = m0 + ty * 4, n = n0 + tx * 4;
#pragma unroll
  for (int i = 0; i < 4; i++) {
    float4 o = {acc[i][0], acc[i][1], acc[i][2], acc[i][3]};
    *(float4*)&C[(size_t)(m + i) * N + n] = o;
  }
}

// ---------------- persistent LSTM: 256 blocks x 512 thr; xg block-private; fence-free barrier ----
__global__ __launch_bounds__(512) void k_lstm_mega(float* __restrict__ ws,
    const int* __restrict__ premise, const int* __restrict__ hyp,
    const int* __restrict__ plen, const int* __restrict__ hlen,
    const float* __restrict__ emb) {
  __shared__ float4 wlds4[2048];   // steps: W [512 k][4 cg] | window: Bx [16 c][304] (19.5KB)
  __shared__ float4 scr4[2048];    // steps: hbuf [128 b][16 k4] swz | window: A [512 r][16 k]
  float* Bx = (float*)wlds4;
  float* Alds = (float*)scr4;

  const int tid = threadIdx.x;
  const int bid = blockIdx.x;
  const int seq = bid >> 7;
  const int li = bid & 127;
  const int T = seq ? THh : TPp;
  const int* toks = seq ? hyp : premise;
  const int* lens = seq ? hlen : plen;
  const float* wstk = ws + (seq ? OFF_WHHT_H : OFF_WHHT_P) + (size_t)li * 8192;
  const float* WX = ws + (seq ? OFF_WIHT_H : OFF_WIHT_P);
  float* hc = ws + (seq ? OFF_HC_H : OFF_HC_P);
  float* xg = ws + OFF_WSM + (size_t)bid * 32768;  // private [tl*128+b][16]
  unsigned* barS = (unsigned*)(ws + (seq ? OFF_BARH : OFF_BARP));
  const int sbase = seq ? 128 : 0;

  const int w = tid >> 6, lane = tid & 63;
  const int cg = w & 3, bh = w >> 2;
  const int b = bh * 64 + lane;
  const int sw = b & 7;
  const int jcol = li * 4 + cg;
  const int len = lens[b];
  float c_r = 0.f, h_r = 0.f;
  int epS = 1;
  int sb[4], sk[4];
#pragma unroll
  for (int j2 = 0; j2 < 4; j2++) { int fi = tid + j2 * 512; sb[j2] = fi >> 4; sk[j2] = fi & 15; }
  const int kofs = (tid & 3) * 4;  // staging k-offset within chunk

  for (int t = 0; t < T; t++) {
    if ((t & 15) == 0) {
      // ---- window: compute private xg for steps t..t+15 (block-local, no grid sync) ----
      __syncthreads();
      for (int i = tid; i < 16 * 304; i += 512) {
        int c = i / 304, kk = i - c * 304;
        int jj = c >> 2, g = c & 3;
        Bx[i] = WX[(size_t)kk * 2048 + g * 512 + li * 4 + jj];
      }
      __syncthreads();
      for (int rg = 0; rg < 4; rg++) {
        int tk[4];
#pragma unroll
        for (int j2 = 0; j2 < 4; j2++) {
          int rl = (tid >> 2) + j2 * 128;
          int R = rg * 512 + rl;
          int tl = R >> 7, bb = R & 127;
          tk[j2] = toks[(size_t)bb * T + t + tl];
        }
        float4 pa[4];
#pragma unroll
        for (int j2 = 0; j2 < 4; j2++) {
          if (kofs + 3 < 300) pa[j2] = *(const float4*)(emb + (size_t)tk[j2] * 300 + kofs);
          else { float4 z = {0.f, 0.f, 0.f, 0.f}; pa[j2] = z; }
        }
        float acc[16];
#pragma unroll
        for (int c = 0; c < 16; c++) acc[c] = 0.f;
        for (int ck = 0; ck < 19; ck++) {
          __syncthreads();
#pragma unroll
          for (int j2 = 0; j2 < 4; j2++) {
            int fi = tid + j2 * 512;
            *(float4*)&Alds[(fi >> 2) * 16 + kofs] = pa[j2];
          }
          __syncthreads();
          if (ck < 18) {
            int kb = (ck + 1) * 16 + kofs;
#pragma unroll
            for (int j2 = 0; j2 < 4; j2++) {
              if (kb + 3 < 300) {
                pa[j2] = *(const float4*)(emb + (size_t)tk[j2] * 300 + kb);
              } else {
                float v0 = (kb + 0 < 300) ? emb[(size_t)tk[j2] * 300 + kb + 0] : (kb + 0 == 303 ? 1.f : 0.f);
                float v1 = (kb + 1 < 300) ? emb[(size_t)tk[j2] * 300 + kb + 1] : (kb + 1 == 303 ? 1.f : 0.f);
                float v2 = (kb + 2 < 300) ? emb[(size_t)tk[j2] * 300 + kb + 2] : (kb + 2 == 303 ? 1.f : 0.f);
                float v3 = (kb + 3 < 300) ? emb[(size_t)tk[j2] * 300 + kb + 3] : (kb + 3 == 303 ? 1.f : 0.f);
                float4 z = {v0, v1, v2, v3}; pa[j2] = z;
              }
            }
          }
          int kb0 = ck * 16;
#pragma unroll
          for (int kk4 = 0; kk4 < 4; kk4++) {
            float4 av = *(float4*)&Alds[tid * 16 + kk4 * 4];
#pragma unroll
            for (int c = 0; c < 16; c++) {
              float4 bv = *(float4*)&Bx[c * 304 + kb0 + kk4 * 4];
              acc[c] += av.x * bv.x + av.y * bv.y + av.z * bv.z + av.w * bv.w;
            }
          }
        }
        int R = rg * 512 + tid;
#pragma unroll
        for (int cq = 0; cq < 4; cq++) {
          float4 o = {acc[cq * 4], acc[cq * 4 + 1], acc[cq * 4 + 2], acc[cq * 4 + 3]};
          *(float4*)&xg[(size_t)R * 16 + cq * 4] = o;
        }
      }
      // restage W for the step phase
      __syncthreads();
      {
        const float4* src = (const float4*)wstk;
#pragma unroll
        for (int j2 = 0; j2 < 4; j2++) wlds4[tid + j2 * 512] = src[tid + j2 * 512];
      }
    }
    // ---- step t ----
    {
      const int par = t & 1;
      const float* hin = hc + (size_t)par * (BB * HH);
      float* hout = hc + (size_t)(par ^ 1) * (BB * HH);
      float4 acc = {0.f, 0.f, 0.f, 0.f};
      float4 pre[4];
#pragma unroll
      for (int j2 = 0; j2 < 4; j2++)
        pre[j2] = aload16(hin + (size_t)sb[j2] * 512 + sk[j2] * 4);
      for (int kc = 0; kc < 512; kc += 64) {
        __syncthreads();
#pragma unroll
        for (int j2 = 0; j2 < 4; j2++)
          scr4[sb[j2] * 16 + (sk[j2] ^ (sb[j2] & 7))] = pre[j2];
        __syncthreads();
        if (kc + 64 < 512) {
#pragma unroll
          for (int j2 = 0; j2 < 4; j2++)
            pre[j2] = aload16(hin + (size_t)sb[j2] * 512 + (kc + 64) + sk[j2] * 4);
        }
#pragma unroll
        for (int kk = 0; kk < 64; kk += 4) {
          int k4 = kk >> 2;
          float4 h4 = scr4[b * 16 + (k4 ^ sw)];
          float4 w0 = wlds4[(kc + kk + 0) * 4 + cg];
          float4 w1 = wlds4[(kc + kk + 1) * 4 + cg];
          float4 w2 = wlds4[(kc + kk + 2) * 4 + cg];
          float4 w3 = wlds4[(kc + kk + 3) * 4 + cg];
          acc.x += h4.x * w0.x + h4.y * w1.x + h4.z * w2.x + h4.w * w3.x;
          acc.y += h4.x * w0.y + h4.y * w1.y + h4.z * w2.y + h4.w * w3.y;
          acc.z += h4.x * w0.z + h4.y * w1.z + h4.z * w2.z + h4.w * w3.z;
          acc.w += h4.x * w0.w + h4.y * w1.w + h4.z * w2.w + h4.w * w3.w;
        }
      }
      float4 x0 = *(const float4*)&xg[(((size_t)(t & 15)) * 128 + b) * 16 + cg * 4];
      float iv = sigmf(acc.x + x0.x), fv = sigmf(acc.y + x0.y);
      float gv = tanh_f(acc.z + x0.z), ov = sigmf(acc.w + x0.w);
      float cn = fv * c_r + iv * gv;
      float hn = ov * tanh_f(cn);
      bool inr = t < len;
      if (inr) { c_r = cn; h_r = hn; }
      if (!seq) ws[OFF_HS + ((size_t)b * TPp + t) * 512 + jcol] = inr ? hn : 0.f;         // [b][t][j]
      else      ws[OFF_HT + ((size_t)t * 512 + jcol) * 128 + b] = inr ? hn : 0.f;         // htT [t][j][b]
      astore4(hout + (size_t)b * 512 + jcol, h_r);
      gbar3(barS, epS, sbase, 128); epS++;
    }
  }
}

// ---------------- persistent match: 128 blocks x 512 thr, 64 x {P1,P2,P3}, fence-free ----------------
__global__ __launch_bounds__(512) void k_match_mega(float* __restrict__ ws,
                                                    const int* __restrict__ hlen) {
  __shared__ float smem[8192];  // 32 KB, phase-shared
  const int tid = threadIdx.x;
  const int bid = blockIdx.x;
  float* qT = ws + OFF_Q;
  float* ghT = ws + OFF_GH;
  float* abufT = ws + OFF_A;
  float* hmT = ws + OFF_HM;
  float* last = ws + OFF_LAST;
  const float* B1 = ws + OFF_WB1T;
  const float* W3 = ws + OFF_WIA;
  const float* htT = ws + OFF_HT;
  unsigned* barM = (unsigned*)(ws + OFF_BARM);

  const int r = tid & 127;
  const int cg = tid >> 7;          // 0..3 (wave-pair uniform)
  const int j3 = bid * 4 + cg;      // P3-owned hidden col
  float c_reg = 0.f;
  float bmp[4];
#pragma unroll
  for (int g = 0; g < 4; g++) bmp[g] = ws[OFF_BM + g * 512 + j3];
  const int hl = hlen[r];
  int ep = 1;

  for (int k = 0; k < THh; k++) {
    // ---------- P1: qT/ghT = ([hmT | htT_k] @ WB1T)^T ; block owns 20 cols, cg splits K ----------
    {
      float acc[20];
#pragma unroll
      for (int cc = 0; cc < 20; cc++) acc[cc] = 0.f;
      const int cbase = bid * 20;
      if (cg < 2) {  // hm half, k in [cg*256, cg*256+256)
        const int kbeg = cg * 256;
        for (int kk = 0; kk < 256; kk += 4) {
          int kx = kbeg + kk;
          float a0 = aload4(&hmT[(size_t)(kx + 0) * 128 + r]);
          float a1 = aload4(&hmT[(size_t)(kx + 1) * 128 + r]);
          float a2 = aload4(&hmT[(size_t)(kx + 2) * 128 + r]);
          float a3 = aload4(&hmT[(size_t)(kx + 3) * 128 + r]);
#pragma unroll
          for (int cc = 0; cc < 20; cc++) {
            float4 bv = *(const float4*)&B1[(size_t)(cbase + cc) * 1024 + kx];
            acc[cc] += a0 * bv.x + a1 * bv.y + a2 * bv.z + a3 * bv.w;
          }
        }
      } else {       // ht half, j in [(cg-2)*256, ...)
        const int kbeg = (cg - 2) * 256;
        const float* hcol = htT + (size_t)k * 65536;  // [j][b] slice of step k
        for (int kk = 0; kk < 256; kk += 4) {
          int kj = kbeg + kk;
          float a0 = hcol[(size_t)(kj + 0) * 128 + r];
          float a1 = hcol[(size_t)(kj + 1) * 128 + r];
          float a2 = hcol[(size_t)(kj + 2) * 128 + r];
          float a3 = hcol[(size_t)(kj + 3) * 128 + r];
#pragma unroll
          for (int cc = 0; cc < 20; cc++) {
            float4 bv = *(const float4*)&B1[(size_t)(cbase + cc) * 1024 + 512 + kj];
            acc[cc] += a0 * bv.x + a1 * bv.y + a2 * bv.z + a3 * bv.w;
          }
        }
      }
      // LDS reduce: (cg0+cg1) and (cg2+cg3), then combine
      float* P1R = smem;  // [2][20][128]
      __syncthreads();
      if (cg & 1) {
#pragma unroll
        for (int cc = 0; cc < 20; cc++) P1R[(((cg >> 1) * 20 + cc) << 7) + r] = acc[cc];
      }
      __syncthreads();
      if (!(cg & 1)) {
#pragma unroll
        for (int cc = 0; cc < 20; cc++) acc[cc] += P1R[(((cg >> 1) * 20 + cc) << 7) + r];
      }
      __syncthreads();
      if (cg == 2) {
#pragma unroll
        for (int cc = 0; cc < 20; cc++) P1R[(cc << 7) + r] = acc[cc];
      }
      __syncthreads();
      if (cg == 0) {
#pragma unroll
        for (int cc = 0; cc < 20; cc++) {
          float val = acc[cc] + P1R[(cc << 7) + r];
          int c = cbase + cc;
          if (c < 512) astore4(&qT[(size_t)c * 128 + r], val);
          else astore4(&ghT[(size_t)(c - 512) * 128 + r], val);
        }
      }
    }
    gbar3(barM, ep, 0, 128); ep++;
    // ---------- P2: attention, one block per batch row ----------
    {
      float* q_lds = smem; float* we_lds = smem + 512; float* e_part = smem + 1024;
      float* e_lds = smem + 1536; float* alpha_lds = smem + 1664; float* red_s = smem + 1792;
      const int b = bid;
      const float* Wsb = ws + OFF_WSM;
      const float* hs = ws + OFF_HS;
      q_lds[tid] = aload4(&qT[(size_t)tid * 128 + b]);
      we_lds[tid] = ws[OFF_WEF + tid];
      __syncthreads();
      {
        int t2 = tid >> 2;
        int gbase = (tid & 3) * 128;
        const float* wsrow = Wsb + ((size_t)b * TPp + t2) * 512 + gbase;
        float s = 0.f;
        for (int ii = 0; ii < 128; ii += 4) {
          float4 wv = *(const float4*)(wsrow + ii);
          float4 qv = *(float4*)&q_lds[gbase + ii];
          float4 ev = *(float4*)&we_lds[gbase + ii];
          s += tanh_f(wv.x + qv.x) * ev.x + tanh_f(wv.y + qv.y) * ev.y +
               tanh_f(wv.z + qv.z) * ev.z + tanh_f(wv.w + qv.w) * ev.w;
        }
        e_part[tid] = s;
      }
      __syncthreads();
      if (tid < 128)
        e_lds[tid] = e_part[tid * 4] + e_part[tid * 4 + 1] + e_part[tid * 4 + 2] + e_part[tid * 4 + 3];
      __syncthreads();
      if (tid < 64) {
        float m = fmaxf(e_lds[tid], e_lds[tid + 64]);
        for (int off = 32; off > 0; off >>= 1) m = fmaxf(m, __shfl_down(m, off));
        if (tid == 0) red_s[0] = m;
      }
      __syncthreads();
      if (tid < 128) alpha_lds[tid] = __expf(e_lds[tid] - red_s[0]);
      __syncthreads();
      if (tid < 64) {
        float s = alpha_lds[tid] + alpha_lds[tid + 64];
        for (int off = 32; off > 0; off >>= 1) s += __shfl_down(s, off);
        if (tid == 0) red_s[1] = 1.f / s;
      }
      __syncthreads();
      {
        float inv = red_s[1];
        float a0 = 0.f;
        const float* hsb = hs + (size_t)b * TPp * 512 + tid;
        for (int t2 = 0; t2 < TPp; t2++) a0 += alpha_lds[t2] * hsb[(size_t)t2 * 512];
        astore4(&abufT[(size_t)tid * 128 + b], a0 * inv);   // abufT [j][b]
      }
    }
    gbar3(barM, ep, 0, 128); ep++;
    // ---------- P3: a @ WIAT + ghT + bm -> cell; block owns 4 j (16 c), cg splits K ----------
    {
      float acc3[16];
#pragma unroll
      for (int cl = 0; cl < 16; cl++) acc3[cl] = 0.f;
      const int cb = bid * 16;
      for (int kk = 0; kk < 128; kk += 4) {
        int kx = cg * 128 + kk;
        float a0 = aload4(&abufT[(size_t)(kx + 0) * 128 + r]);
        float a1 = aload4(&abufT[(size_t)(kx + 1) * 128 + r]);
        float a2 = aload4(&abufT[(size_t)(kx + 2) * 128 + r]);
        float a3 = aload4(&abufT[(size_t)(kx + 3) * 128 + r]);
#pragma unroll
        for (int cl = 0; cl < 16; cl++) {
          float4 wv = *(const float4*)&W3[(size_t)(cb + cl) * 512 + kx];
          acc3[cl] += a0 * wv.x + a1 * wv.y + a2 * wv.z + a3 * wv.w;
        }
      }
      float* P3R = smem;  // [4 kq][16 cl][128 r] = 8192
      __syncthreads();
#pragma unroll
      for (int cl = 0; cl < 16; cl++) P3R[((cg * 16 + cl) << 7) + r] = acc3[cl];
      __syncthreads();
      float g4[4];
#pragma unroll
      for (int g = 0; g < 4; g++) {
        int cl = cg * 4 + g;
        float s = P3R[((0 * 16 + cl) << 7) + r] + P3R[((1 * 16 + cl) << 7) + r] +
                  P3R[((2 * 16 + cl) << 7) + r] + P3R[((3 * 16 + cl) << 7) + r];
        g4[g] = s + aload4(&ghT[(size_t)(j3 * 4 + g) * 128 + r]) + bmp[g];
      }
      float iv = sigmf(g4[0]), fv = sigmf(g4[1]), gg = tanh_f(g4[2]), ov = sigmf(g4[3]);
      float cn = fv * c_reg + iv * gg;
      float hn = ov * tanh_f(cn);
      c_reg = cn;
      astore4(&hmT[(size_t)j3 * 128 + r], hn);
      if (k == hl - 1) last[(size_t)r * 512 + j3] = hn;
    }
    gbar3(barM, ep, 0, 128); ep++;
  }
}

// ---------------- FC epilogue ----------------
__global__ __launch_bounds__(256) void k_fc(const float* __restrict__ ws, const float* __restrict__ Wfc,
                                            const float* __restrict__ bfc, float* __restrict__ out) {
  int idx = blockIdx.x * 256 + threadIdx.x;
  if (idx >= BB * 3) return;
  int b = idx / 3, o = idx - b * 3;
  const float* lrow = ws + OFF_LAST + (size_t)b * 512;
  const float* wrow = Wfc + (size_t)o * 512;
  float acc = bfc[o];
  for (int h = 0; h < 512; h++) acc += lrow[h] * wrow[h];
  out[idx] = acc;
}

extern "C" void kernel_launch(void* const* d_in, const int* in_sizes, int n_in, void* d_out,
                              int out_size, void* d_ws, size_t ws_size, hipStream_t stream) {
  const int* premise = (const int*)d_in[0];
  const int* plen = (const int*)d_in[1];
  const int* hyp = (const int*)d_in[2];
  const int* hlen = (const int*)d_in[3];
  const float* emb = (const float*)d_in[4];
  const float* Wih_p = (const float*)d_in[5];
  const float* Whh_p = (const float*)d_in[6];
  const float* bih_p = (const float*)d_in[7];
  const float* bhh_p = (const float*)d_in[8];
  const float* Wih_h = (const float*)d_in[9];
  const float* Whh_h = (const float*)d_in[10];
  const float* bih_h = (const float*)d_in[11];
  const float* bhh_h = (const float*)d_in[12];
  const float* Wih_m = (const float*)d_in[13];
  const float* Whh_m = (const float*)d_in[14];
  const float* bih_m = (const float*)d_in[15];
  const float* bhh_m = (const float*)d_in[16];
  const float* w_e = (const float*)d_in[17];
  const float* W_s = (const float*)d_in[18];
  const float* W_t = (const float*)d_in[19];
  const float* W_m = (const float*)d_in[20];
  const float* W_fc = (const float*)d_in[21];
  const float* b_fc = (const float*)d_in[22];
  float* ws = (float*)d_ws;
  float* out = (float*)d_out;

  if (ws_size < WS_FLOATS * sizeof(float)) {
    float mb = (float)((double)ws_size / (1024.0 * 1024.0));
    k_diag<<<dim3(6), dim3(64), 0, stream>>>(out, mb);
    return;
  }

  // K0: weight prep + state/slot zero
  {
    size_t total = 2 * SZ_WIHT + 2 * (size_t)512 * 2048 + (size_t)2560 * 1024 +
                   (size_t)2048 * 512 + 512 + 2048 + 393216 + 131072 + 13824;
    int nb = (int)((total + 255) / 256);
    k_prep<<<dim3(nb), dim3(256), 0, stream>>>(ws, Wih_p, bih_p, bhh_p, Wih_h, bih_h, bhh_h,
                                               Whh_p, Whh_h, Whh_m, Wih_m, bih_m, bhh_m,
                                               W_m, W_t, w_e);
  }
  // persistent LSTM (fence-free barriers, private xg)
  {
    void* args[] = {(void*)&ws, (void*)&premise, (void*)&hyp, (void*)&plen, (void*)&hlen, (void*)&emb};
    hipError_t e = hipLaunchCooperativeKernel((const void*)k_lstm_mega, dim3(256), dim3(512),
                                              args, 0, stream);
    if (e != hipSuccess)
      k_lstm_mega<<<dim3(256), dim3(512), 0, stream>>>(ws, premise, hyp, plen, hlen, emb);
  }
  // Ws = HS @ W_s^T (WSM region free again)
  k_gemm<<<dim3(256 * 8), dim3(256), 0, stream>>>(ws + OFF_HS, W_s, 512, 512, 512,
                                                  ws + OFF_WSM, 8);
  // persistent match loop (128 blocks, 3 fence-free barriers/step)
  {
    void* args[] = {(void*)&ws, (void*)&hlen};
    hipError_t e = hipLaunchCooperativeKernel((const void*)k_match_mega, dim3(128), dim3(512),
                                              args, 0, stream);
    if (e != hipSuccess)
      k_match_mega<<<dim3(128), dim3(512), 0, stream>>>(ws, hlen);
  }
  // FC epilogue
  k_fc<<<dim3(2), dim3(256), 0, stream>>>(ws, W_fc, b_fc, out);
}

// Round 6
// 11810.096 us; speedup vs baseline: 1.3169x; 1.3169x over previous
//
#include <hip/hip_runtime.h>

// Problem constants
constexpr int BB = 128;   // batch
constexpr int TPp = 128;  // premise len
constexpr int THh = 64;   // hypothesis len
constexpr int HH = 512;   // hidden

// ---------------- workspace layout (fp32 words) ----------------
constexpr size_t OFF_HS     = 0;                               // premise h history [b][t][512]
constexpr size_t SZ_HS      = (size_t)16384 * 512;
constexpr size_t OFF_HT     = OFF_HS + SZ_HS;                  // hyp h history [b][t][512]
constexpr size_t SZ_HT      = (size_t)8192 * 512;
constexpr size_t OFF_WSM    = OFF_HT + SZ_HT;                  // Ws [16384][512] (match) / LSTM private xg
constexpr size_t SZ_WSM     = (size_t)16384 * 512;
constexpr size_t OFF_WIHT_P = OFF_WSM + SZ_WSM;                // [304 k][2048 c] rows 300-302 zero, 303=bih+bhh
constexpr size_t SZ_WIHT    = (size_t)304 * 2048;
constexpr size_t OFF_WIHT_H = OFF_WIHT_P + SZ_WIHT;
constexpr size_t OFF_WHHT_P = OFF_WIHT_H + SZ_WIHT;            // WSTK_P [128 li][512 k][16 c] c=jj*4+g
constexpr size_t OFF_WHHT_H = OFF_WHHT_P + (size_t)512 * 2048;
constexpr size_t OFF_WB1T   = OFF_WHHT_H + (size_t)512 * 2048; // [2560 c][1024 k]
constexpr size_t OFF_WIA    = OFF_WB1T + (size_t)2560 * 1024;  // WIAT [2048 c][512 k], c=j*4+g
constexpr size_t OFF_WEF    = OFF_WIA + (size_t)2048 * 512;    // w_e [512]
constexpr size_t OFF_BM     = OFF_WEF + 512;                   // bih_m+bhh_m [2048]
constexpr size_t OFF_HC_P   = OFF_BM + 2048;                   // 2 x [128][512] h carry dbuf (premise)
constexpr size_t OFF_HC_H   = OFF_HC_P + 2 * (size_t)BB * HH;  // 2 x [128][512] (hyp)
constexpr size_t OFF_C_P    = OFF_HC_H + 2 * (size_t)BB * HH;  // vestigial (zeroed)
constexpr size_t OFF_C_H    = OFF_C_P + (size_t)BB * HH;
constexpr size_t OFF_Q      = OFF_C_H + (size_t)BB * HH;       // qT [512 c][128 r]
constexpr size_t OFF_GH     = OFF_Q + (size_t)BB * HH;         // ghT [2048 c][128 r], c=j*4+g
constexpr size_t OFF_A      = OFF_GH + (size_t)BB * 2048;      // abuf [128 b][512 j]
constexpr size_t OFF_HM     = OFF_A + (size_t)BB * HH;         // hm [128 r][512 j]
constexpr size_t OFF_CM     = OFF_HM + (size_t)BB * HH;        // vestigial (zeroed)
constexpr size_t OFF_LAST   = OFF_CM + (size_t)BB * HH;        // [128 r][512 j]
constexpr size_t OFF_BARP   = OFF_LAST + (size_t)BB * HH;      // premise barrier slots (2560)
constexpr size_t OFF_BARH   = OFF_BARP + 2560;                 // hyp barrier slots (2560)
constexpr size_t OFF_BARF   = OFF_BARH + 2560;                 // unused (4352, zeroed)
constexpr size_t OFF_BARM   = OFF_BARF + 4352;                 // match barrier slots (4352)
constexpr size_t WS_FLOATS  = OFF_BARM + 4352;

__device__ __forceinline__ float sigmf(float x) { return 1.0f / (1.0f + __expf(-x)); }
__device__ __forceinline__ float tanh_f(float x) {
  float e = __expf(-2.0f * fabsf(x));
  float r = (1.0f - e) / (1.0f + e);
  return copysignf(r, x);
}

// ---- device-coherent access: serviced at coherence point, never stale-cached ----
__device__ __forceinline__ float aload4(const float* p) {
  unsigned u = __hip_atomic_load((const unsigned*)p, __ATOMIC_RELAXED, __HIP_MEMORY_SCOPE_AGENT);
  return __uint_as_float(u);
}
__device__ __forceinline__ void astore4(float* p, float v) {
  __hip_atomic_store((unsigned*)p, __float_as_uint(v), __ATOMIC_RELAXED, __HIP_MEMORY_SCOPE_AGENT);
}
__device__ __forceinline__ float4 aload16(const float* p) {
  const unsigned long long* q = (const unsigned long long*)p;
  unsigned long long u0 = __hip_atomic_load(q, __ATOMIC_RELAXED, __HIP_MEMORY_SCOPE_AGENT);
  unsigned long long u1 = __hip_atomic_load(q + 1, __ATOMIC_RELAXED, __HIP_MEMORY_SCOPE_AGENT);
  union { unsigned long long u; float2 f; } c0, c1;
  c0.u = u0; c1.u = u1;
  float4 f; f.x = c0.f.x; f.y = c0.f.y; f.z = c1.f.x; f.w = c1.f.y;
  return f;
}

// ---- fence-free slot barrier over blocks [base, base+n). NO buffer_wbl2/buffer_inv.
// All cross-block mutable data uses device-scope atomics; release = s_waitcnt only.
__device__ __forceinline__ void gbar3(unsigned* bar, int ep, int base, int n) {
  asm volatile("s_waitcnt vmcnt(0) lgkmcnt(0)" ::: "memory");
  __syncthreads();
  const int tid = threadIdx.x;
  const int rel = (int)blockIdx.x - base;
  if (tid == 0)
    __hip_atomic_store(bar + (size_t)rel * 16, (unsigned)ep,
                       __ATOMIC_RELAXED, __HIP_MEMORY_SCOPE_AGENT);
  if (rel == 0) {
    for (int s = tid; s < n; s += (int)blockDim.x)
      while (__hip_atomic_load(bar + (size_t)s * 16,
                               __ATOMIC_RELAXED, __HIP_MEMORY_SCOPE_AGENT) < (unsigned)ep)
        __builtin_amdgcn_s_sleep(1);
    __syncthreads();
    if (tid == 0)
      __hip_atomic_store(bar + (size_t)n * 16, (unsigned)ep,
                         __ATOMIC_RELAXED, __HIP_MEMORY_SCOPE_AGENT);
  } else if (tid == 0) {
    while (__hip_atomic_load(bar + (size_t)n * 16,
                             __ATOMIC_RELAXED, __HIP_MEMORY_SCOPE_AGENT) < (unsigned)ep)
      __builtin_amdgcn_s_sleep(1);
  }
  __syncthreads();
}

// ---------------- diag ----------------
__global__ void k_diag(float* out, float v) {
  int i = blockIdx.x * 64 + threadIdx.x;
  if (i < BB * 3) out[i] = v;
}

// ---------------- K0: weight transpose/stack + state/slot zero ----------------
__global__ __launch_bounds__(256) void k_prep(float* ws,
    const float* Wih_p, const float* bih_p, const float* bhh_p,
    const float* Wih_h, const float* bih_h, const float* bhh_h,
    const float* Whh_p, const float* Whh_h,
    const float* Whh_m, const float* Wih_m, const float* bih_m, const float* bhh_m,
    const float* W_m, const float* W_t, const float* w_e) {
  size_t gid = (size_t)blockIdx.x * 256 + threadIdx.x;
  if (gid < SZ_WIHT) {
    int k = (int)(gid >> 11), r = (int)(gid & 2047);
    float v = (k < 300) ? Wih_p[(size_t)r * 300 + k]
            : (k == 303) ? (bih_p[r] + bhh_p[r]) : 0.f;
    ws[OFF_WIHT_P + gid] = v;
    return;
  }
  gid -= SZ_WIHT;
  if (gid < SZ_WIHT) {
    int k = (int)(gid >> 11), r = (int)(gid & 2047);
    float v = (k < 300) ? Wih_h[(size_t)r * 300 + k]
            : (k == 303) ? (bih_h[r] + bhh_h[r]) : 0.f;
    ws[OFF_WIHT_H + gid] = v;
    return;
  }
  gid -= SZ_WIHT;
  const size_t NT = (size_t)512 * 2048;
  if (gid < NT) {  // WSTK_P
    int li = (int)(gid >> 13);
    int rem = (int)(gid & 8191);
    int k = rem >> 4, c = rem & 15;
    int jj = c >> 2, g = c & 3;
    ws[OFF_WHHT_P + gid] = Whh_p[(size_t)(g * 512 + li * 4 + jj) * 512 + k];
    return;
  }
  gid -= NT;
  if (gid < NT) {  // WSTK_H
    int li = (int)(gid >> 13);
    int rem = (int)(gid & 8191);
    int k = rem >> 4, c = rem & 15;
    int jj = c >> 2, g = c & 3;
    ws[OFF_WHHT_H + gid] = Whh_h[(size_t)(g * 512 + li * 4 + jj) * 512 + k];
    return;
  }
  gid -= NT;
  if (gid < (size_t)2560 * 1024) {  // WB1T [c][k]
    int c = (int)(gid >> 10), k = (int)(gid & 1023);
    float v;
    if (c < 512) {
      v = (k < 512) ? W_m[(size_t)c * 512 + k] : W_t[(size_t)c * 512 + (k - 512)];
    } else {
      int p = c - 512;
      int j = p >> 2, g = p & 3;
      int r = g * 512 + j;
      v = (k < 512) ? Whh_m[(size_t)r * 512 + k] : Wih_m[(size_t)r * 1024 + k];
    }
    ws[OFF_WB1T + gid] = v;
    return;
  }
  gid -= (size_t)2560 * 1024;
  if (gid < (size_t)2048 * 512) {  // WIAT [c][k]
    int c = (int)(gid >> 9), k = (int)(gid & 511);
    int j = c >> 2, g = c & 3;
    ws[OFF_WIA + gid] = Wih_m[((size_t)g * 512 + j) * 1024 + k];
    return;
  }
  gid -= (size_t)2048 * 512;
  if (gid < 512) { ws[OFF_WEF + gid] = w_e[gid]; return; }
  gid -= 512;
  if (gid < 2048) { ws[OFF_BM + gid] = bih_m[gid] + bhh_m[gid]; return; }
  gid -= 2048;
  if (gid < (size_t)393216) { ws[OFF_HC_P + gid] = 0.f; return; }  // HC_P,HC_H,C_P,C_H
  gid -= 393216;
  if (gid < (size_t)131072) { ws[OFF_HM + gid] = 0.f; return; }    // HM, CM
  gid -= 131072;
  if (gid < 13824) { ws[OFF_BARP + gid] = 0.f; return; }           // ALL barrier slots
}

// ---------------- generic 64x64-tile fp32 GEMM (Ws = HS @ W_s^T) ----------------
__global__ __launch_bounds__(256) void k_gemm(const float* __restrict__ A,
                                              const float* __restrict__ Bw, int ldb, int Kdim,
                                              int N, float* __restrict__ C, int ntilesN) {
  __shared__ float As[16][68];
  __shared__ float Bs[16][68];
  const int tid = threadIdx.x;
  const int bid = blockIdx.x;
  const int tm = bid / ntilesN, tn = bid % ntilesN;
  const int m0 = tm * 64, n0 = tn * 64;
  const int tx = tid & 15, ty = tid >> 4;
  const int srow = tid >> 2, skc = (tid & 3) * 4;
  float acc[4][4] = {};
  const float* arowf = A + (size_t)(m0 + srow) * Kdim;
  const float* brow = Bw + (size_t)(n0 + srow) * ldb;
  for (int k0 = 0; k0 < Kdim; k0 += 16) {
    float4 v = *(const float4*)(arowf + k0 + skc);
    As[skc + 0][srow] = v.x; As[skc + 1][srow] = v.y;
    As[skc + 2][srow] = v.z; As[skc + 3][srow] = v.w;
#pragma unroll
    for (int i = 0; i < 4; i++) Bs[skc + i][srow] = brow[k0 + skc + i];
    __syncthreads();
#pragma unroll
    for (int kk = 0; kk < 16; kk++) {
      float4 a4 = *(float4*)&As[kk][ty * 4];
      float4 b4 = *(float4*)&Bs[kk][tx * 4];
      acc[0][0] += a4.x * b4.x; acc[0][1] += a4.x * b4.y; acc[0][2] += a4.x * b4.z; acc[0][3] += a4.x * b4.w;
      acc[1][0] += a4.y * b4.x; acc[1][1] += a4.y * b4.y; acc[1][2] += a4.y * b4.z; acc[1][3] += a4.y * b4.w;
      acc[2][0] += a4.z * b4.x; acc[2][1] += a4.z * b4.y; acc[2][2] += a4.z * b4.z; acc[2][3] += a4.z * b4.w;
      acc[3][0] += a4.w * b4.x; acc[3][1] += a4.w * b4.y; acc[3][2] += a4.w * b4.z; acc[3][3] += a4.w * b4.w;
    }
    __syncthreads();
  }
  const int m = m0 + ty * 4, n = n0 + tx * 4;
#pragma unroll
  for (int i = 0; i < 4; i++) {
    float4 o = {acc[i][0], acc[i][1], acc[i][2], acc[i][3]};
    *(float4*)&C[(size_t)(m + i) * N + n] = o;
  }
}

// ---------------- persistent LSTM: 256 blocks x 512 thr; xg block-private; fence-free barrier ----
__global__ __launch_bounds__(512) void k_lstm_mega(float* __restrict__ ws,
    const int* __restrict__ premise, const int* __restrict__ hyp,
    const int* __restrict__ plen, const int* __restrict__ hlen,
    const float* __restrict__ emb) {
  __shared__ float4 wlds4[2048];   // steps: W [512 k][4 cg] | window: Bx [16 c][304]
  __shared__ float4 scr4[2048];    // steps: hbuf [128 b][16 k4] swz | window: A [512 r][16 k]
  float* Bx = (float*)wlds4;
  float* Alds = (float*)scr4;

  const int tid = threadIdx.x;
  const int bid = blockIdx.x;
  const int seq = bid >> 7;
  const int li = bid & 127;
  const int T = seq ? THh : TPp;
  const int* toks = seq ? hyp : premise;
  const int* lens = seq ? hlen : plen;
  const float* wstk = ws + (seq ? OFF_WHHT_H : OFF_WHHT_P) + (size_t)li * 8192;
  const float* WX = ws + (seq ? OFF_WIHT_H : OFF_WIHT_P);
  float* hc = ws + (seq ? OFF_HC_H : OFF_HC_P);
  float* xg = ws + OFF_WSM + (size_t)bid * 32768;  // private [tl*128+b][16]
  unsigned* barS = (unsigned*)(ws + (seq ? OFF_BARH : OFF_BARP));
  const int sbase = seq ? 128 : 0;

  const int w = tid >> 6, lane = tid & 63;
  const int cg = w & 3, bh = w >> 2;
  const int b = bh * 64 + lane;
  const int sw = b & 7;
  const int jcol = li * 4 + cg;
  const int len = lens[b];
  float c_r = 0.f, h_r = 0.f;
  int epS = 1;
  int sb[4], sk[4];
#pragma unroll
  for (int j2 = 0; j2 < 4; j2++) { int fi = tid + j2 * 512; sb[j2] = fi >> 4; sk[j2] = fi & 15; }
  const int kofs = (tid & 3) * 4;

  for (int t = 0; t < T; t++) {
    if ((t & 15) == 0) {
      // ---- window: compute private xg for steps t..t+15 (block-local) ----
      __syncthreads();
      for (int i = tid; i < 16 * 304; i += 512) {
        int c = i / 304, kk = i - c * 304;
        int jj = c >> 2, g = c & 3;
        Bx[i] = WX[(size_t)kk * 2048 + g * 512 + li * 4 + jj];
      }
      __syncthreads();
      for (int rg = 0; rg < 4; rg++) {
        int tk[4];
#pragma unroll
        for (int j2 = 0; j2 < 4; j2++) {
          int rl = (tid >> 2) + j2 * 128;
          int R = rg * 512 + rl;
          int tl = R >> 7, bb = R & 127;
          tk[j2] = toks[(size_t)bb * T + t + tl];
        }
        float4 pa[4];
#pragma unroll
        for (int j2 = 0; j2 < 4; j2++) {
          if (kofs + 3 < 300) pa[j2] = *(const float4*)(emb + (size_t)tk[j2] * 300 + kofs);
          else { float4 z = {0.f, 0.f, 0.f, 0.f}; pa[j2] = z; }
        }
        float acc[16];
#pragma unroll
        for (int c = 0; c < 16; c++) acc[c] = 0.f;
        for (int ck = 0; ck < 19; ck++) {
          __syncthreads();
#pragma unroll
          for (int j2 = 0; j2 < 4; j2++) {
            int fi = tid + j2 * 512;
            *(float4*)&Alds[(fi >> 2) * 16 + kofs] = pa[j2];
          }
          __syncthreads();
          if (ck < 18) {
            int kb = (ck + 1) * 16 + kofs;
#pragma unroll
            for (int j2 = 0; j2 < 4; j2++) {
              if (kb + 3 < 300) {
                pa[j2] = *(const float4*)(emb + (size_t)tk[j2] * 300 + kb);
              } else {
                float v0 = (kb + 0 < 300) ? emb[(size_t)tk[j2] * 300 + kb + 0] : (kb + 0 == 303 ? 1.f : 0.f);
                float v1 = (kb + 1 < 300) ? emb[(size_t)tk[j2] * 300 + kb + 1] : (kb + 1 == 303 ? 1.f : 0.f);
                float v2 = (kb + 2 < 300) ? emb[(size_t)tk[j2] * 300 + kb + 2] : (kb + 2 == 303 ? 1.f : 0.f);
                float v3 = (kb + 3 < 300) ? emb[(size_t)tk[j2] * 300 + kb + 3] : (kb + 3 == 303 ? 1.f : 0.f);
                float4 z = {v0, v1, v2, v3}; pa[j2] = z;
              }
            }
          }
          int kb0 = ck * 16;
#pragma unroll
          for (int kk4 = 0; kk4 < 4; kk4++) {
            float4 av = *(float4*)&Alds[tid * 16 + kk4 * 4];
#pragma unroll
            for (int c = 0; c < 16; c++) {
              float4 bv = *(float4*)&Bx[c * 304 + kb0 + kk4 * 4];
              acc[c] += av.x * bv.x + av.y * bv.y + av.z * bv.z + av.w * bv.w;
            }
          }
        }
        int R = rg * 512 + tid;
#pragma unroll
        for (int cq = 0; cq < 4; cq++) {
          float4 o = {acc[cq * 4], acc[cq * 4 + 1], acc[cq * 4 + 2], acc[cq * 4 + 3]};
          *(float4*)&xg[(size_t)R * 16 + cq * 4] = o;
        }
      }
      __syncthreads();
      {
        const float4* src = (const float4*)wstk;
#pragma unroll
        for (int j2 = 0; j2 < 4; j2++) wlds4[tid + j2 * 512] = src[tid + j2 * 512];
      }
    }
    // ---- step t ----
    {
      const int par = t & 1;
      const float* hin = hc + (size_t)par * (BB * HH);
      float* hout = hc + (size_t)(par ^ 1) * (BB * HH);
      float4 acc = {0.f, 0.f, 0.f, 0.f};
      float4 pre[4];
#pragma unroll
      for (int j2 = 0; j2 < 4; j2++)
        pre[j2] = aload16(hin + (size_t)sb[j2] * 512 + sk[j2] * 4);
      for (int kc = 0; kc < 512; kc += 64) {
        __syncthreads();
#pragma unroll
        for (int j2 = 0; j2 < 4; j2++)
          scr4[sb[j2] * 16 + (sk[j2] ^ (sb[j2] & 7))] = pre[j2];
        __syncthreads();
        if (kc + 64 < 512) {
#pragma unroll
          for (int j2 = 0; j2 < 4; j2++)
            pre[j2] = aload16(hin + (size_t)sb[j2] * 512 + (kc + 64) + sk[j2] * 4);
        }
#pragma unroll
        for (int kk = 0; kk < 64; kk += 4) {
          int k4 = kk >> 2;
          float4 h4 = scr4[b * 16 + (k4 ^ sw)];
          float4 w0 = wlds4[(kc + kk + 0) * 4 + cg];
          float4 w1 = wlds4[(kc + kk + 1) * 4 + cg];
          float4 w2 = wlds4[(kc + kk + 2) * 4 + cg];
          float4 w3 = wlds4[(kc + kk + 3) * 4 + cg];
          acc.x += h4.x * w0.x + h4.y * w1.x + h4.z * w2.x + h4.w * w3.x;
          acc.y += h4.x * w0.y + h4.y * w1.y + h4.z * w2.y + h4.w * w3.y;
          acc.z += h4.x * w0.z + h4.y * w1.z + h4.z * w2.z + h4.w * w3.z;
          acc.w += h4.x * w0.w + h4.y * w1.w + h4.z * w2.w + h4.w * w3.w;
        }
      }
      float4 x0 = *(const float4*)&xg[(((size_t)(t & 15)) * 128 + b) * 16 + cg * 4];
      float iv = sigmf(acc.x + x0.x), fv = sigmf(acc.y + x0.y);
      float gv = tanh_f(acc.z + x0.z), ov = sigmf(acc.w + x0.w);
      float cn = fv * c_r + iv * gv;
      float hn = ov * tanh_f(cn);
      bool inr = t < len;
      if (inr) { c_r = cn; h_r = hn; }
      if (!seq) ws[OFF_HS + ((size_t)b * TPp + t) * 512 + jcol] = inr ? hn : 0.f;  // [b][t][j]
      else      ws[OFF_HT + ((size_t)b * THh + t) * 512 + jcol] = inr ? hn : 0.f;  // [b][t][j]
      astore4(hout + (size_t)b * 512 + jcol, h_r);
      gbar3(barS, epS, sbase, 128); epS++;
    }
  }
}

// ---------------- persistent match: 256 blocks x 512 thr, 64 x {P1,P2,P3} ----------------
// LDS: B1 [10][1024] 40KB + W3 [8][512] 16KB (both staged ONCE) + 8KB phase-shared tile/scratch.
// Wave-pairs: (h5 = col/j group, khh = K half); LDS partial reduce combines K halves.
// Mutable cross-block data (hm,qT,ghT,abuf) via device-scope atomics; read-only via cached loads.
__global__ __launch_bounds__(512) void k_match_mega(float* __restrict__ ws,
                                                    const int* __restrict__ hlen) {
  __shared__ float smem[16384];  // 64 KB exactly
  float* B1 = smem;              // [10][1024]
  float* W3 = smem + 10240;      // [8][512]
  float4* AL4 = (float4*)(smem + 14336);  // 512 float4 = 8KB staging tile
  float* SCR = smem + 14336;              // aliases AL4 (2048 floats)

  const int tid = threadIdx.x;
  const int bid = blockIdx.x;
  float* hm = ws + OFF_HM;        // [r][512]
  const float* ht = ws + OFF_HT;  // [b][t][512]
  float* qT = ws + OFF_Q;         // [512 c][128 r]
  float* ghT = ws + OFF_GH;       // [2048 c][128 r]
  float* abuf = ws + OFF_A;       // [b][512]
  float* last = ws + OFF_LAST;
  unsigned* barM = (unsigned*)(ws + OFF_BARM);

  // stage persistent weight slices once
  {
    const float* src = ws + OFF_WB1T + (size_t)bid * 10240;
    for (int i = tid; i < 10240; i += 512) B1[i] = src[i];
    const float* s2 = ws + OFF_WIA + (size_t)bid * 4096;
    for (int i = tid; i < 4096; i += 512) W3[i] = s2[i];
  }
  const int r = tid & 127;
  const int khh = (tid >> 7) & 1;   // K-half (wave-pair uniform)
  const int h5 = tid >> 8;          // col group (wave-pair uniform)
  const int j3 = bid * 2 + h5;      // P3-owned hidden col
  // staging map: 1 float4/thread: skh = source half, sq4 = k-quad, sbv = b
  const int skh = tid >> 8, sq4 = (tid >> 7) & 1, sbv = tid & 127;
  float c_reg = 0.f;
  float bmp[4];
#pragma unroll
  for (int g = 0; g < 4; g++) bmp[g] = ws[OFF_BM + g * 512 + j3];
  const int hl = hlen[r];
  int ep = 1;
  __syncthreads();

  for (int k = 0; k < THh; k++) {
    // ---------- P1: qT/ghT = ([hm | ht_k] @ WB1T)^T ; 10 cols/block; khh splits K ----------
    {
      float acc[5] = {0.f, 0.f, 0.f, 0.f, 0.f};
      float4 p = (skh == 0) ? aload16(&hm[(size_t)sbv * 512 + sq4 * 4])
                            : *(const float4*)&ht[((size_t)sbv * THh + k) * 512 + sq4 * 4];
      for (int ch = 0; ch < 64; ch++) {
        __syncthreads();
        AL4[skh * 256 + sq4 * 128 + sbv] = p;
        __syncthreads();
        if (ch < 63) {
          int kn = (ch + 1) * 8 + sq4 * 4;
          p = (skh == 0) ? aload16(&hm[(size_t)sbv * 512 + kn])
                         : *(const float4*)&ht[((size_t)sbv * THh + k) * 512 + kn];
        }
        const int kb = khh * 512 + ch * 8;
#pragma unroll
        for (int q4 = 0; q4 < 2; q4++) {
          float4 av = AL4[khh * 256 + q4 * 128 + r];
#pragma unroll
          for (int cc = 0; cc < 5; cc++) {
            float4 bv = *(float4*)&B1[(h5 * 5 + cc) * 1024 + kb + q4 * 4];  // wave-uniform
            acc[cc] += av.x * bv.x + av.y * bv.y + av.z * bv.z + av.w * bv.w;
          }
        }
      }
      __syncthreads();
      if (khh == 1) {
#pragma unroll
        for (int cc = 0; cc < 5; cc++) SCR[(h5 * 5 + cc) * 128 + r] = acc[cc];
      }
      __syncthreads();
      if (khh == 0) {
#pragma unroll
        for (int cc = 0; cc < 5; cc++) {
          float val = acc[cc] + SCR[(h5 * 5 + cc) * 128 + r];
          int c = bid * 10 + h5 * 5 + cc;
          if (c < 512) astore4(&qT[(size_t)c * 128 + r], val);
          else astore4(&ghT[(size_t)(c - 512) * 128 + r], val);
        }
      }
    }
    gbar3(barM, ep, 0, 256); ep++;
    // ---------- P2: attention (blocks 0..127, one per batch row) ----------
    if (bid < 128) {
      float* q_lds = SCR; float* we_lds = SCR + 512; float* e_part = SCR + 1024;
      float* e_lds = SCR + 1536; float* alpha_lds = SCR + 1664; float* red_s = SCR + 1792;
      const int b = bid;
      const float* Wsb = ws + OFF_WSM;
      const float* hs = ws + OFF_HS;
      q_lds[tid] = aload4(&qT[(size_t)tid * 128 + b]);
      we_lds[tid] = ws[OFF_WEF + tid];
      __syncthreads();
      {
        int t2 = tid >> 2;
        int gbase = (tid & 3) * 128;
        const float* wsrow = Wsb + ((size_t)b * TPp + t2) * 512 + gbase;
        float s = 0.f;
        for (int ii = 0; ii < 128; ii += 4) {
          float4 wv = *(const float4*)(wsrow + ii);
          float4 qv = *(float4*)&q_lds[gbase + ii];
          float4 ev = *(float4*)&we_lds[gbase + ii];
          s += tanh_f(wv.x + qv.x) * ev.x + tanh_f(wv.y + qv.y) * ev.y +
               tanh_f(wv.z + qv.z) * ev.z + tanh_f(wv.w + qv.w) * ev.w;
        }
        e_part[tid] = s;
      }
      __syncthreads();
      if (tid < 128)
        e_lds[tid] = e_part[tid * 4] + e_part[tid * 4 + 1] + e_part[tid * 4 + 2] + e_part[tid * 4 + 3];
      __syncthreads();
      if (tid < 64) {
        float m = fmaxf(e_lds[tid], e_lds[tid + 64]);
        for (int off = 32; off > 0; off >>= 1) m = fmaxf(m, __shfl_down(m, off));
        if (tid == 0) red_s[0] = m;
      }
      __syncthreads();
      if (tid < 128) alpha_lds[tid] = __expf(e_lds[tid] - red_s[0]);
      __syncthreads();
      if (tid < 64) {
        float s = alpha_lds[tid] + alpha_lds[tid + 64];
        for (int off = 32; off > 0; off >>= 1) s += __shfl_down(s, off);
        if (tid == 0) red_s[1] = 1.f / s;
      }
      __syncthreads();
      {
        float inv = red_s[1];
        float a0 = 0.f;
        const float* hsb = hs + (size_t)b * TPp * 512 + tid;
        for (int t2 = 0; t2 < TPp; t2++) a0 += alpha_lds[t2] * hsb[(size_t)t2 * 512];
        astore4(&abuf[(size_t)b * 512 + tid], a0 * inv);   // coalesced
      }
    }
    gbar3(barM, ep, 0, 256); ep++;
    // ---------- P3: a @ WIAT + ghT + bm -> cell; 2 j/block; khh splits K ----------
    {
      float acc3[4] = {0.f, 0.f, 0.f, 0.f};
      float4 p3 = aload16(&abuf[(size_t)sbv * 512 + skh * 256 + sq4 * 4]);
      for (int ch = 0; ch < 32; ch++) {
        __syncthreads();
        AL4[skh * 256 + sq4 * 128 + sbv] = p3;
        __syncthreads();
        if (ch < 31) {
          int kn = skh * 256 + (ch + 1) * 8 + sq4 * 4;
          p3 = aload16(&abuf[(size_t)sbv * 512 + kn]);
        }
        const int kb = khh * 256 + ch * 8;
#pragma unroll
        for (int q4 = 0; q4 < 2; q4++) {
          float4 av = AL4[khh * 256 + q4 * 128 + r];
#pragma unroll
          for (int cc = 0; cc < 4; cc++) {
            float4 wv = *(float4*)&W3[(h5 * 4 + cc) * 512 + kb + q4 * 4];  // wave-uniform
            acc3[cc] += av.x * wv.x + av.y * wv.y + av.z * wv.z + av.w * wv.w;
          }
        }
      }
      __syncthreads();
      if (khh == 1) {
#pragma unroll
        for (int cc = 0; cc < 4; cc++) SCR[(h5 * 4 + cc) * 128 + r] = acc3[cc];
      }
      __syncthreads();
      if (khh == 0) {
        float g4[4];
#pragma unroll
        for (int g = 0; g < 4; g++) {
          g4[g] = acc3[g] + SCR[(h5 * 4 + g) * 128 + r] +
                  aload4(&ghT[(size_t)(j3 * 4 + g) * 128 + r]) + bmp[g];
        }
        float iv = sigmf(g4[0]), fv = sigmf(g4[1]), gg = tanh_f(g4[2]), ov = sigmf(g4[3]);
        float cn = fv * c_reg + iv * gg;
        float hn = ov * tanh_f(cn);
        c_reg = cn;
        astore4(&hm[(size_t)r * 512 + j3], hn);
        if (k == hl - 1) last[(size_t)r * 512 + j3] = hn;
      }
    }
    gbar3(barM, ep, 0, 256); ep++;
  }
}

// ---------------- FC epilogue ----------------
__global__ __launch_bounds__(256) void k_fc(const float* __restrict__ ws, const float* __restrict__ Wfc,
                                            const float* __restrict__ bfc, float* __restrict__ out) {
  int idx = blockIdx.x * 256 + threadIdx.x;
  if (idx >= BB * 3) return;
  int b = idx / 3, o = idx - b * 3;
  const float* lrow = ws + OFF_LAST + (size_t)b * 512;
  const float* wrow = Wfc + (size_t)o * 512;
  float acc = bfc[o];
  for (int h = 0; h < 512; h++) acc += lrow[h] * wrow[h];
  out[idx] = acc;
}

extern "C" void kernel_launch(void* const* d_in, const int* in_sizes, int n_in, void* d_out,
                              int out_size, void* d_ws, size_t ws_size, hipStream_t stream) {
  const int* premise = (const int*)d_in[0];
  const int* plen = (const int*)d_in[1];
  const int* hyp = (const int*)d_in[2];
  const int* hlen = (const int*)d_in[3];
  const float* emb = (const float*)d_in[4];
  const float* Wih_p = (const float*)d_in[5];
  const float* Whh_p = (const float*)d_in[6];
  const float* bih_p = (const float*)d_in[7];
  const float* bhh_p = (const float*)d_in[8];
  const float* Wih_h = (const float*)d_in[9];
  const float* Whh_h = (const float*)d_in[10];
  const float* bih_h = (const float*)d_in[11];
  const float* bhh_h = (const float*)d_in[12];
  const float* Wih_m = (const float*)d_in[13];
  const float* Whh_m = (const float*)d_in[14];
  const float* bih_m = (const float*)d_in[15];
  const float* bhh_m = (const float*)d_in[16];
  const float* w_e = (const float*)d_in[17];
  const float* W_s = (const float*)d_in[18];
  const float* W_t = (const float*)d_in[19];
  const float* W_m = (const float*)d_in[20];
  const float* W_fc = (const float*)d_in[21];
  const float* b_fc = (const float*)d_in[22];
  float* ws = (float*)d_ws;
  float* out = (float*)d_out;

  if (ws_size < WS_FLOATS * sizeof(float)) {
    float mb = (float)((double)ws_size / (1024.0 * 1024.0));
    k_diag<<<dim3(6), dim3(64), 0, stream>>>(out, mb);
    return;
  }

  // K0: weight prep + state/slot zero
  {
    size_t total = 2 * SZ_WIHT + 2 * (size_t)512 * 2048 + (size_t)2560 * 1024 +
                   (size_t)2048 * 512 + 512 + 2048 + 393216 + 131072 + 13824;
    int nb = (int)((total + 255) / 256);
    k_prep<<<dim3(nb), dim3(256), 0, stream>>>(ws, Wih_p, bih_p, bhh_p, Wih_h, bih_h, bhh_h,
                                               Whh_p, Whh_h, Whh_m, Wih_m, bih_m, bhh_m,
                                               W_m, W_t, w_e);
  }
  // persistent LSTM (fence-free barriers, private xg)
  {
    void* args[] = {(void*)&ws, (void*)&premise, (void*)&hyp, (void*)&plen, (void*)&hlen, (void*)&emb};
    hipError_t e = hipLaunchCooperativeKernel((const void*)k_lstm_mega, dim3(256), dim3(512),
                                              args, 0, stream);
    if (e != hipSuccess)
      k_lstm_mega<<<dim3(256), dim3(512), 0, stream>>>(ws, premise, hyp, plen, hlen, emb);
  }
  // Ws = HS @ W_s^T (WSM region free again)
  k_gemm<<<dim3(256 * 8), dim3(256), 0, stream>>>(ws + OFF_HS, W_s, 512, 512, 512,
                                                  ws + OFF_WSM, 8);
  // persistent match loop (256 blocks, LDS-resident weights, 3 fence-free barriers/step)
  {
    void* args[] = {(void*)&ws, (void*)&hlen};
    hipError_t e = hipLaunchCooperativeKernel((const void*)k_match_mega, dim3(256), dim3(512),
                                              args, 0, stream);
    if (e != hipSuccess)
      k_match_mega<<<dim3(256), dim3(512), 0, stream>>>(ws, hlen);
  }
  // FC epilogue
  k_fc<<<dim3(2), dim3(256), 0, stream>>>(ws, W_fc, b_fc, out);
}